// Round 6
// baseline (140.613 us; speedup 1.0000x reference)
//
#include <hip/hip_runtime.h>

// B=8192, J=17, F=128. f32 in/out.
// ws layout (float index):
//   [0, 32768)        : 128 slots x (128 sum + 128 sumsq) BN partials (memset 0 per launch)
//   [32768, 33024)    : stats: scale[128], shift[128]
//   [33024, 33313)    : off_sym[17*17]
//   [33313, 33330)    : diag[17]
//   [33344, 49728)    : W^T bf16 [256 cols][128 k] = 32768 shorts = 16384 floats (64KB)
//   [49728, ...)      : bf16 pre-BN activations [139264*128] (35.7MB) if ws_size allows
// R5 lesson: __launch_bounds__(512,8) -> 64-reg cap -> acc spills (WRITE 125MB). Use (512,4).

#define NSLOT      128
#define OFF_PART   0
#define OFF_STATS  32768
#define OFF_OFFSYM 33024
#define OFF_DIAG   33313
#define OFF_WBT    33344
#define OFF_PRE    49728
#define PRE_SHORTS (139264ull * 128ull)

typedef __attribute__((ext_vector_type(8))) short bf16x8;
typedef __attribute__((ext_vector_type(4))) float f32x4;
typedef union { unsigned u[4]; bf16x8 v; } pkU;

__device__ __forceinline__ short f2bf(float f) {
    unsigned u = __float_as_uint(f);
    u += 0x7FFFu + ((u >> 16) & 1u);   // round-to-nearest-even
    return (short)(u >> 16);
}
__device__ __forceinline__ float bf2f(short h) {
    return __uint_as_float(((unsigned)(unsigned short)h) << 16);
}
__device__ __forceinline__ float bflo(int p) {
    return __uint_as_float(((unsigned)p) << 16);
}
__device__ __forceinline__ float bfhi(int p) {
    return __uint_as_float(((unsigned)p) & 0xFFFF0000u);
}
// one v_cvt_pk_bf16_f32: low16 = bf16(a), high16 = bf16(b), RNE
__device__ __forceinline__ unsigned pk2(float a, float b) {
    unsigned r;
    asm("v_cvt_pk_bf16_f32 %0, %1, %2" : "=v"(r) : "v"(a), "v"(b));
    return r;
}

// ---------------- prep: 17 blocks. blk0: adjacency; blk1..16: W^T bf16 ----------------
__global__ __launch_bounds__(256) void prep_kernel(
    const float* __restrict__ W, const float* __restrict__ adj,
    const float* __restrict__ adj2, float* __restrict__ wsf)
{
    const int t = threadIdx.x, b = blockIdx.x;
    if (b == 0) {
        for (int e = t; e < 289; e += 256) {
            int i = e / 17, j = e % 17;
            float v = 0.5f * (adj[i*17+j] + adj2[i*17+j] + adj[j*17+i] + adj2[j*17+i]);
            if (i == j) { wsf[OFF_DIAG + i] = v; v = 0.f; }
            wsf[OFF_OFFSYM + i*17 + j] = v;
        }
        return;
    }
    short* wbt = (short*)(wsf + OFF_WBT);
    const int col = (b - 1) * 16 + (t >> 4);
    const int k0  = (t & 15) * 8;
    const int sel = col >> 7, colp = col & 127;
    const float* src = W + sel * 16384 + colp;   // W[sel][k][colp]
    bf16x8 p;
    #pragma unroll
    for (int e = 0; e < 8; ++e) p[e] = f2bf(src[(k0 + e) * 128]);
    *(bf16x8*)(wbt + col * 128 + k0) = p;
}

// ---------------- conv: 68 rows/block; A-frags loaded DIRECT from global ----------
// LDS: hh (68x130 ints = 35.4KB, reused as red[1024]) + offs. No A staging.
template<int USE_BF16>
__global__ __launch_bounds__(512, 4) void conv_kernel(
    const float* __restrict__ x, const float* __restrict__ M,
    const float* __restrict__ bias, float* ws,
    float* __restrict__ out, short* __restrict__ pre)
{
    __shared__ int hhI[68 * 130];
    __shared__ float offs[292];

    const int tid = threadIdx.x;
    const int w = tid >> 6, l = tid & 63, c = l & 15, g = l >> 4;

    for (int e = tid; e < 289; e += 512) offs[e] = ws[OFF_OFFSYM + e];

    // ---- MFMA: wave w owns col = w*16+c for h0 (col) and h1 (col+128) ----
    const float* xt = x + (size_t)blockIdx.x * (68 * 128);
    const short* wbt = (const short*)(ws + OFF_WBT);
    const int col = w * 16 + c;
    f32x4 acc0[5], acc1[5];
    #pragma unroll
    for (int mt = 0; mt < 5; ++mt) {
        acc0[mt] = (f32x4){0.f, 0.f, 0.f, 0.f};
        acc1[mt] = (f32x4){0.f, 0.f, 0.f, 0.f};
    }
    #pragma unroll
    for (int ks = 0; ks < 4; ++ks) {
        bf16x8 b0 = *(const bf16x8*)(wbt + col * 128 + ks * 32 + g * 8);
        bf16x8 b1 = *(const bf16x8*)(wbt + (col + 128) * 128 + ks * 32 + g * 8);
        #pragma unroll
        for (int mt = 0; mt < 5; ++mt) {
            // lane (c,g) IS A-row mt*16+c, k-slice ks*32+g*8 (32B contiguous).
            // mt=4: rows 68..79 don't exist -> clamp to 64+(c&3); results for
            // frag-rows>=4 are discarded by the row<68 guard below.
            const int arow = (mt < 4) ? (mt * 16 + c) : (64 + (c & 3));
            const float* ap = xt + arow * 128 + ks * 32 + g * 8;
            float4 lo = *(const float4*)ap;
            float4 hi = *(const float4*)(ap + 4);
            pkU pu;
            pu.u[0] = pk2(lo.x, lo.y); pu.u[1] = pk2(lo.z, lo.w);
            pu.u[2] = pk2(hi.x, hi.y); pu.u[3] = pk2(hi.z, hi.w);
            acc0[mt] = __builtin_amdgcn_mfma_f32_16x16x32_bf16(pu.v, b0, acc0[mt], 0, 0, 0);
            acc1[mt] = __builtin_amdgcn_mfma_f32_16x16x32_bf16(pu.v, b1, acc1[mt], 0, 0, 0);
        }
    }

    // ---- epilogue: fold diag/M/bias, pack (hh0,hh1) one dword per (row,col) ----
    const float bv = bias[col];
    #pragma unroll
    for (int mt = 0; mt < 5; ++mt) {
        #pragma unroll
        for (int r = 0; r < 4; ++r) {
            int row = mt * 16 + g * 4 + r;
            if (row < 68) {
                int j = row - 17 * ((row * 241) >> 12);   // row % 17 (valid to 67)
                float m  = M[j * 128 + col];
                float dg = ws[OFF_DIAG + j];
                float lo = fmaf(dg * m, acc0[mt][r], bv); // diag*M*h0 + bias
                float hi = m * acc1[mt][r];               // M*h1
                hhI[row * 130 + col] = (int)pk2(lo, hi);
            }
        }
    }
    __syncthreads();   // hh ready (also covers offs)

    // ---- mixing: thread -> (bb = tid>>7, o = tid&127); 17 rows each ----
    const int bb = tid >> 7, o = tid & 127;
    const int rb = bb * 17;
    int pj[17];
    #pragma unroll
    for (int i = 0; i < 17; ++i) pj[i] = hhI[(rb + i) * 130 + o];
    __syncthreads();   // pj reads done; hhI reusable as red

    float vout[17];
    #pragma unroll
    for (int q = 0; q < 17; ++q) vout[q] = bflo(pj[q]);
    #pragma unroll
    for (int j = 0; j < 17; ++j) {
        float h1v = bfhi(pj[j]);
        #pragma unroll
        for (int q = 0; q < 17; ++q)
            vout[q] = fmaf(offs[q * 17 + j], h1v, vout[q]);
    }

    float s = 0.f, s2 = 0.f;
    const size_t gbase = ((size_t)blockIdx.x * 68 + rb) * 128 + o;
    #pragma unroll
    for (int q = 0; q < 17; ++q) {
        float v = vout[q];
        if (USE_BF16) pre[gbase + (size_t)q * 128] = (short)pk2(v, v);
        else          out[gbase + (size_t)q * 128] = v;
        s += v; s2 = fmaf(v, v, s2);
    }

    // ---- BN partials: block LDS reduce (in hhI) then 256 lane-atomics ----
    float* red = (float*)hhI;
    red[tid] = s; red[512 + tid] = s2;
    __syncthreads();
    if (tid < 128) {
        float ts = red[tid] + red[tid + 128] + red[tid + 256] + red[tid + 384];
        float t2 = red[512 + tid] + red[512 + tid + 128] +
                   red[512 + tid + 256] + red[512 + tid + 384];
        float* slot = ws + OFF_PART + ((blockIdx.x & (NSLOT - 1)) << 8);
        atomicAdd(slot + tid, ts);
        atomicAdd(slot + 128 + tid, t2);
    }
}

// ---------------- BN stats reduce ----------------
__global__ __launch_bounds__(256) void bn_reduce_kernel(
    const float* __restrict__ part, const float* __restrict__ gamma,
    const float* __restrict__ beta, float* __restrict__ stats)
{
    const int t = threadIdx.x;             // 0..255
    float s = 0.f;
    #pragma unroll 8
    for (int i = 0; i < NSLOT; ++i) s += part[i * 256 + t];
    __shared__ float tot[256];
    tot[t] = s;
    __syncthreads();
    if (t < 128) {
        const float n = 139264.f;          // 8192*17
        float mean = tot[t] / n;
        float var  = tot[t + 128] / n - mean * mean;
        var = fmaxf(var, 0.f);
        float inv = rsqrtf(var + 1e-5f);
        float sc = gamma[t] * inv;
        stats[t] = sc;
        stats[t + 128] = beta[t] - mean * sc;
    }
}

// ---------------- BN apply + relu: bf16 pre (ws) -> f32 out ----------------
__global__ __launch_bounds__(256) void apply_bf16_kernel(
    const short* __restrict__ pre, const float* __restrict__ stats,
    float* __restrict__ out)
{
    const int tid = blockIdx.x * 256 + threadIdx.x;
    const int c0 = (tid << 3) & 127;       // stride (524288*8) % 128 == 0
    float sc[8], sh[8];
    #pragma unroll
    for (int e = 0; e < 8; ++e) { sc[e] = stats[c0 + e]; sh[e] = stats[128 + c0 + e]; }
    const bf16x8* p8 = (const bf16x8*)pre;
    for (int q = tid; q < 2228224; q += 524288) {
        bf16x8 v = p8[q];
        float4 o0, o1;
        o0.x = fmaxf(fmaf(bf2f(v[0]), sc[0], sh[0]), 0.f);
        o0.y = fmaxf(fmaf(bf2f(v[1]), sc[1], sh[1]), 0.f);
        o0.z = fmaxf(fmaf(bf2f(v[2]), sc[2], sh[2]), 0.f);
        o0.w = fmaxf(fmaf(bf2f(v[3]), sc[3], sh[3]), 0.f);
        o1.x = fmaxf(fmaf(bf2f(v[4]), sc[4], sh[4]), 0.f);
        o1.y = fmaxf(fmaf(bf2f(v[5]), sc[5], sh[5]), 0.f);
        o1.z = fmaxf(fmaf(bf2f(v[6]), sc[6], sh[6]), 0.f);
        o1.w = fmaxf(fmaf(bf2f(v[7]), sc[7], sh[7]), 0.f);
        float4* dst = (float4*)(out + (size_t)q * 8);
        dst[0] = o0; dst[1] = o1;
    }
}

// ---------------- BN apply + relu fallback (in-place f32) ----------------
__global__ __launch_bounds__(256) void apply_kernel(
    float* __restrict__ out, const float* __restrict__ stats, int n4)
{
    const int tid = blockIdx.x * 256 + threadIdx.x;
    const int c0 = (tid << 2) & 127;
    const float sc0 = stats[c0],     sc1 = stats[c0 + 1],
                sc2 = stats[c0 + 2], sc3 = stats[c0 + 3];
    const float sh0 = stats[128 + c0],     sh1 = stats[128 + c0 + 1],
                sh2 = stats[128 + c0 + 2], sh3 = stats[128 + c0 + 3];
    float4* o4 = (float4*)out;
    for (int q = tid; q < n4; q += 2048 * 256) {
        float4 v = o4[q];
        v.x = fmaxf(fmaf(v.x, sc0, sh0), 0.f);
        v.y = fmaxf(fmaf(v.y, sc1, sh1), 0.f);
        v.z = fmaxf(fmaf(v.z, sc2, sh2), 0.f);
        v.w = fmaxf(fmaf(v.w, sc3, sh3), 0.f);
        o4[q] = v;
    }
}

extern "C" void kernel_launch(void* const* d_in, const int* in_sizes, int n_in,
                              void* d_out, int out_size, void* d_ws, size_t ws_size,
                              hipStream_t stream) {
    (void)in_sizes; (void)n_in; (void)out_size;
    const float* x     = (const float*)d_in[0];
    const float* W     = (const float*)d_in[1];
    const float* M     = (const float*)d_in[2];
    const float* adj   = (const float*)d_in[3];
    const float* adj2  = (const float*)d_in[4];
    const float* bias  = (const float*)d_in[5];
    const float* gamma = (const float*)d_in[6];
    const float* beta  = (const float*)d_in[7];
    float* out = (float*)d_out;
    float* wsf = (float*)d_ws;
    short* pre = (short*)(wsf + OFF_PRE);

    const bool big = ws_size >= (size_t)OFF_PRE * 4 + PRE_SHORTS * 2;

    hipMemsetAsync(d_ws, 0, NSLOT * 256 * sizeof(float), stream);   // BN partial slots
    prep_kernel<<<17, 256, 0, stream>>>(W, adj, adj2, wsf);
    if (big) {
        conv_kernel<1><<<2048, 512, 0, stream>>>(x, M, bias, wsf, out, pre);
        bn_reduce_kernel<<<1, 256, 0, stream>>>(wsf + OFF_PART, gamma, beta, wsf + OFF_STATS);
        apply_bf16_kernel<<<2048, 256, 0, stream>>>(pre, wsf + OFF_STATS, out);
    } else {
        conv_kernel<0><<<2048, 512, 0, stream>>>(x, M, bias, wsf, out, pre);
        bn_reduce_kernel<<<1, 256, 0, stream>>>(wsf + OFF_PART, gamma, beta, wsf + OFF_STATS);
        apply_kernel<<<2048, 256, 0, stream>>>(out, wsf + OFF_STATS, 4456448);
    }
}

// Round 9
// 82.063 us; speedup vs baseline: 1.7135x; 1.7135x over previous
//
#include <hip/hip_runtime.h>

// B=8192, J=17, F=128. f32 in/out.
// ws layout (float index):
//   [0, 32768)        : 128 slots x (128 sum + 128 sumsq) BN partials (memset 0 per launch)
//   [32768, 33024)    : stats: scale[128], shift[128]
//   [33024, 33313)    : off_sym[17*17]
//   [33313, 33330)    : diag[17]
//   [33344, 49728)    : W^T bf16 [256 cols][128 k] = 32768 shorts = 16384 floats (64KB)
//   [49728, ...)      : bf16 pre-BN activations [139264*128] (35.7MB) if ws_size allows
// R5: no 64-reg cap (spills). R6: keep A in LDS. R7: no &vec[i].
// R8: all-zero out; prime suspect = misaligned float4 LDS store (Mlds) -> dropped.

#define NSLOT      128
#define OFF_PART   0
#define OFF_STATS  32768
#define OFF_OFFSYM 33024
#define OFF_DIAG   33313
#define OFF_WBT    33344
#define OFF_PRE    49728
#define PRE_SHORTS (139264ull * 128ull)

typedef __attribute__((ext_vector_type(8))) short bf16x8;
typedef __attribute__((ext_vector_type(4))) short bf16x4;
typedef __attribute__((ext_vector_type(4))) float f32x4;
typedef union { unsigned u[2]; bf16x4 v; } pk4U;

__device__ __forceinline__ short f2bf(float f) {
    unsigned u = __float_as_uint(f);
    u += 0x7FFFu + ((u >> 16) & 1u);   // round-to-nearest-even
    return (short)(u >> 16);
}
__device__ __forceinline__ float bf2f(short h) {
    return __uint_as_float(((unsigned)(unsigned short)h) << 16);
}
__device__ __forceinline__ float bflo(int p) {
    return __uint_as_float(((unsigned)p) << 16);
}
__device__ __forceinline__ float bfhi(int p) {
    return __uint_as_float(((unsigned)p) & 0xFFFF0000u);
}
// one v_cvt_pk_bf16_f32: low16 = bf16(a), high16 = bf16(b), RNE
__device__ __forceinline__ unsigned pk2(float a, float b) {
    unsigned r;
    asm("v_cvt_pk_bf16_f32 %0, %1, %2" : "=v"(r) : "v"(a), "v"(b));
    return r;
}

// ---------------- prep: 17 blocks. blk0: adjacency; blk1..16: W^T bf16 ----------------
__global__ __launch_bounds__(256) void prep_kernel(
    const float* __restrict__ W, const float* __restrict__ adj,
    const float* __restrict__ adj2, float* __restrict__ wsf)
{
    const int t = threadIdx.x, b = blockIdx.x;
    if (b == 0) {
        for (int e = t; e < 289; e += 256) {
            int i = e / 17, j = e % 17;
            float v = 0.5f * (adj[i*17+j] + adj2[i*17+j] + adj[j*17+i] + adj2[j*17+i]);
            if (i == j) { wsf[OFF_DIAG + i] = v; v = 0.f; }
            wsf[OFF_OFFSYM + i*17 + j] = v;
        }
        return;
    }
    short* wbt = (short*)(wsf + OFF_WBT);
    const int col = (b - 1) * 16 + (t >> 4);
    const int k0  = (t & 15) * 8;
    const int sel = col >> 7, colp = col & 127;
    const float* src = W + sel * 16384 + colp;   // W[sel][k][colp]
    bf16x8 p;
    #pragma unroll
    for (int e = 0; e < 8; ++e) p[e] = f2bf(src[(k0 + e) * 128]);
    *(bf16x8*)(wbt + col * 128 + k0) = p;
}

// ---------------- conv: 68 rows/block, MFMA bf16 ("R4 structure @ 68 rows") ----------
// LDS: hhI[68*130] ints (35.4KB), aliased as A-tile short[80][136] in phase 1 and
// red[1024] floats in the reduce; offs[292]. ~36.6KB -> 4 blocks/CU.
template<int USE_BF16>
__global__ __launch_bounds__(512, 4) void conv_kernel(
    const float* __restrict__ x, const float* __restrict__ M,
    const float* __restrict__ bias, float* ws,
    float* __restrict__ out, short* __restrict__ pre)
{
    __shared__ int hhI[68 * 130];
    __shared__ float offs[292];
    short (*A)[136] = (short(*)[136])hhI;   // 80 rows (12 zero-pad)

    const int tid = threadIdx.x;
    const int w = tid >> 6, l = tid & 63, c = l & 15, g = l >> 4;

    for (int e = tid; e < 289; e += 512) offs[e] = ws[OFF_OFFSYM + e];

    // ---- stage x[blk*68 .. +68) f32 -> bf16 LDS (2176 float4) ----
    const float4* xsrc = (const float4*)(x + (size_t)blockIdx.x * (68 * 128));
    #pragma unroll
    for (int it = 0; it < 5; ++it) {
        int f = tid + it * 512;
        if (f < 2176) {
            float4 v = xsrc[f];
            int r = f >> 5, k0 = (f & 31) << 2;
            pk4U p;
            p.u[0] = pk2(v.x, v.y);
            p.u[1] = pk2(v.z, v.w);
            *(bf16x4*)&A[r][k0] = p.v;
        }
    }
    if (tid < 408) {                       // zero pad rows 68..79 (12*136 shorts)
        bf16x4 z = {0, 0, 0, 0};
        ((bf16x4*)&A[68][0])[tid] = z;
    }
    __syncthreads();

    // ---- K-loop: wave w owns col = w*16+c for h0 (col) and h1 (col+128) ----
    const short* wbt = (const short*)(ws + OFF_WBT);
    const int col = w * 16 + c;
    f32x4 acc0[5], acc1[5];
    #pragma unroll
    for (int mt = 0; mt < 5; ++mt) {
        acc0[mt] = (f32x4){0.f, 0.f, 0.f, 0.f};
        acc1[mt] = (f32x4){0.f, 0.f, 0.f, 0.f};
    }
    #pragma unroll
    for (int ks = 0; ks < 4; ++ks) {
        bf16x8 b0 = *(const bf16x8*)(wbt + col * 128 + ks * 32 + g * 8);
        bf16x8 b1 = *(const bf16x8*)(wbt + (col + 128) * 128 + ks * 32 + g * 8);
        #pragma unroll
        for (int mt = 0; mt < 5; ++mt) {
            bf16x8 af = *(const bf16x8*)&A[mt * 16 + c][ks * 32 + g * 8];
            acc0[mt] = __builtin_amdgcn_mfma_f32_16x16x32_bf16(af, b0, acc0[mt], 0, 0, 0);
            acc1[mt] = __builtin_amdgcn_mfma_f32_16x16x32_bf16(af, b1, acc1[mt], 0, 0, 0);
        }
    }
    __syncthreads();   // all A reads done before hh overwrites the union

    // ---- epilogue (R4-proven): fold diag/M/bias, pack one dword per (row,col) ----
    const float bv = bias[col];
    #pragma unroll
    for (int mt = 0; mt < 5; ++mt) {
        #pragma unroll
        for (int r = 0; r < 4; ++r) {
            int row = mt * 16 + g * 4 + r;
            if (row < 68) {
                int j = row - 17 * ((row * 241) >> 12);   // row % 17 (valid to 67)
                float m  = M[j * 128 + col];
                float dg = ws[OFF_DIAG + j];
                float lo = fmaf(dg * m, acc0[mt][r], bv); // diag*M*h0 + bias
                float hi = m * acc1[mt][r];               // M*h1
                hhI[row * 130 + col] = (int)pk2(lo, hi);
            }
        }
    }
    __syncthreads();   // hh ready

    // ---- mixing: thread -> (bb = tid>>7, o = tid&127); 17 rows each ----
    const int bb = tid >> 7, o = tid & 127;
    const int rb = bb * 17;
    int pj[17];
    #pragma unroll
    for (int i = 0; i < 17; ++i) pj[i] = hhI[(rb + i) * 130 + o];
    __syncthreads();   // pj reads done; hhI reusable as red

    float vout[17];
    #pragma unroll
    for (int q = 0; q < 17; ++q) vout[q] = bflo(pj[q]);
    #pragma unroll
    for (int j = 0; j < 17; ++j) {
        float h1v = bfhi(pj[j]);
        #pragma unroll
        for (int q = 0; q < 17; ++q)
            vout[q] = fmaf(offs[q * 17 + j], h1v, vout[q]);
    }

    float s = 0.f, s2 = 0.f;
    const size_t gbase = ((size_t)blockIdx.x * 68 + rb) * 128 + o;
    #pragma unroll
    for (int q = 0; q < 17; ++q) {
        float v = vout[q];
        if (USE_BF16) pre[gbase + (size_t)q * 128] = (short)pk2(v, v);
        else          out[gbase + (size_t)q * 128] = v;
        s += v; s2 = fmaf(v, v, s2);
    }

    // ---- BN partials: block LDS reduce (in hhI) then 256 lane-atomics ----
    float* red = (float*)hhI;
    red[tid] = s; red[512 + tid] = s2;
    __syncthreads();
    if (tid < 128) {
        float ts = red[tid] + red[tid + 128] + red[tid + 256] + red[tid + 384];
        float t2 = red[512 + tid] + red[512 + tid + 128] +
                   red[512 + tid + 256] + red[512 + tid + 384];
        float* slot = ws + OFF_PART + ((blockIdx.x & (NSLOT - 1)) << 8);
        atomicAdd(slot + tid, ts);
        atomicAdd(slot + 128 + tid, t2);
    }
}

// ---------------- BN stats reduce ----------------
__global__ __launch_bounds__(256) void bn_reduce_kernel(
    const float* __restrict__ part, const float* __restrict__ gamma,
    const float* __restrict__ beta, float* __restrict__ stats)
{
    const int t = threadIdx.x;             // 0..255
    float s = 0.f;
    #pragma unroll 8
    for (int i = 0; i < NSLOT; ++i) s += part[i * 256 + t];
    __shared__ float tot[256];
    tot[t] = s;
    __syncthreads();
    if (t < 128) {
        const float n = 139264.f;          // 8192*17
        float mean = tot[t] / n;
        float var  = tot[t + 128] / n - mean * mean;
        var = fmaxf(var, 0.f);
        float inv = rsqrtf(var + 1e-5f);
        float sc = gamma[t] * inv;
        stats[t] = sc;
        stats[t + 128] = beta[t] - mean * sc;
    }
}

// ---------------- BN apply + relu: bf16 pre (ws) -> f32 out ----------------
__global__ __launch_bounds__(256) void apply_bf16_kernel(
    const short* __restrict__ pre, const float* __restrict__ stats,
    float* __restrict__ out)
{
    const int tid = blockIdx.x * 256 + threadIdx.x;
    const int c0 = (tid << 3) & 127;       // stride (524288*8) % 128 == 0
    float sc[8], sh[8];
    #pragma unroll
    for (int e = 0; e < 8; ++e) { sc[e] = stats[c0 + e]; sh[e] = stats[128 + c0 + e]; }
    const bf16x8* p8 = (const bf16x8*)pre;
    for (int q = tid; q < 2228224; q += 524288) {
        bf16x8 v = p8[q];
        float4 o0, o1;
        o0.x = fmaxf(fmaf(bf2f(v[0]), sc[0], sh[0]), 0.f);
        o0.y = fmaxf(fmaf(bf2f(v[1]), sc[1], sh[1]), 0.f);
        o0.z = fmaxf(fmaf(bf2f(v[2]), sc[2], sh[2]), 0.f);
        o0.w = fmaxf(fmaf(bf2f(v[3]), sc[3], sh[3]), 0.f);
        o1.x = fmaxf(fmaf(bf2f(v[4]), sc[4], sh[4]), 0.f);
        o1.y = fmaxf(fmaf(bf2f(v[5]), sc[5], sh[5]), 0.f);
        o1.z = fmaxf(fmaf(bf2f(v[6]), sc[6], sh[6]), 0.f);
        o1.w = fmaxf(fmaf(bf2f(v[7]), sc[7], sh[7]), 0.f);
        float4* dst = (float4*)(out + (size_t)q * 8);
        dst[0] = o0; dst[1] = o1;
    }
}

// ---------------- BN apply + relu fallback (in-place f32) ----------------
__global__ __launch_bounds__(256) void apply_kernel(
    float* __restrict__ out, const float* __restrict__ stats, int n4)
{
    const int tid = blockIdx.x * 256 + threadIdx.x;
    const int c0 = (tid << 2) & 127;
    const float sc0 = stats[c0],     sc1 = stats[c0 + 1],
                sc2 = stats[c0 + 2], sc3 = stats[c0 + 3];
    const float sh0 = stats[128 + c0],     sh1 = stats[128 + c0 + 1],
                sh2 = stats[128 + c0 + 2], sh3 = stats[128 + c0 + 3];
    float4* o4 = (float4*)out;
    for (int q = tid; q < n4; q += 2048 * 256) {
        float4 v = o4[q];
        v.x = fmaxf(fmaf(v.x, sc0, sh0), 0.f);
        v.y = fmaxf(fmaf(v.y, sc1, sh1), 0.f);
        v.z = fmaxf(fmaf(v.z, sc2, sh2), 0.f);
        v.w = fmaxf(fmaf(v.w, sc3, sh3), 0.f);
        o4[q] = v;
    }
}

extern "C" void kernel_launch(void* const* d_in, const int* in_sizes, int n_in,
                              void* d_out, int out_size, void* d_ws, size_t ws_size,
                              hipStream_t stream) {
    (void)in_sizes; (void)n_in; (void)out_size;
    const float* x     = (const float*)d_in[0];
    const float* W     = (const float*)d_in[1];
    const float* M     = (const float*)d_in[2];
    const float* adj   = (const float*)d_in[3];
    const float* adj2  = (const float*)d_in[4];
    const float* bias  = (const float*)d_in[5];
    const float* gamma = (const float*)d_in[6];
    const float* beta  = (const float*)d_in[7];
    float* out = (float*)d_out;
    float* wsf = (float*)d_ws;
    short* pre = (short*)(wsf + OFF_PRE);

    const bool big = ws_size >= (size_t)OFF_PRE * 4 + PRE_SHORTS * 2;

    (void)hipMemsetAsync(d_ws, 0, NSLOT * 256 * sizeof(float), stream);   // BN partials
    prep_kernel<<<17, 256, 0, stream>>>(W, adj, adj2, wsf);
    if (big) {
        conv_kernel<1><<<2048, 512, 0, stream>>>(x, M, bias, wsf, out, pre);
        bn_reduce_kernel<<<1, 256, 0, stream>>>(wsf + OFF_PART, gamma, beta, wsf + OFF_STATS);
        apply_bf16_kernel<<<2048, 256, 0, stream>>>(pre, wsf + OFF_STATS, out);
    } else {
        conv_kernel<0><<<2048, 512, 0, stream>>>(x, M, bias, wsf, out, pre);
        bn_reduce_kernel<<<1, 256, 0, stream>>>(wsf + OFF_PART, gamma, beta, wsf + OFF_STATS);
        apply_kernel<<<2048, 256, 0, stream>>>(out, wsf + OFF_STATS, 4456448);
    }
}

// Round 11
// 80.323 us; speedup vs baseline: 1.7506x; 1.0217x over previous
//
#include <hip/hip_runtime.h>

// B=8192, J=17, F=128. f32 in/out.
// ws layout (float index):
//   [0, 32768)        : 128 slots x (128 sum + 128 sumsq) BN partials (memset 0 per launch)
//   [32768, 33024)    : stats: scale[128], shift[128]
//   [33024, 33364)    : off_sym padded [17][20] (rows 16B-aligned; symmetric; pads zeroed)
//   [33364, 33381)    : diag[17]
//   [33408, 49792)    : W^T bf16 [256 cols][128 k] = 32768 shorts = 16384 floats (64KB)
//   [49792, ...)      : bf16 pre-BN activations [139264*128] (35.7MB) if ws_size allows
// R5: no 64-reg cap (spills). R6: keep A in LDS. R7: no &vec[i]. R8: no unaligned
// float4 LDS stores. R10 lesson: bundled rewrites fail undebuggably -> bisect from
// R9. R11 = R9 + {vectorized offs rows, direct BN atomics} ONLY.

#define NSLOT      128
#define OFF_PART   0
#define OFF_STATS  32768
#define OFF_OFFSYM 33024
#define OFF_DIAG   33364
#define OFF_WBT    33408
#define OFF_PRE    49792
#define PRE_SHORTS (139264ull * 128ull)

typedef __attribute__((ext_vector_type(8))) short bf16x8;
typedef __attribute__((ext_vector_type(4))) short bf16x4;
typedef __attribute__((ext_vector_type(4))) float f32x4;
typedef union { unsigned u[2]; bf16x4 v; } pk4U;

__device__ __forceinline__ short f2bf(float f) {
    unsigned u = __float_as_uint(f);
    u += 0x7FFFu + ((u >> 16) & 1u);   // round-to-nearest-even
    return (short)(u >> 16);
}
__device__ __forceinline__ float bf2f(short h) {
    return __uint_as_float(((unsigned)(unsigned short)h) << 16);
}
__device__ __forceinline__ float bflo(int p) {
    return __uint_as_float(((unsigned)p) << 16);
}
__device__ __forceinline__ float bfhi(int p) {
    return __uint_as_float(((unsigned)p) & 0xFFFF0000u);
}
// one v_cvt_pk_bf16_f32: low16 = bf16(a), high16 = bf16(b), RNE
__device__ __forceinline__ unsigned pk2(float a, float b) {
    unsigned r;
    asm("v_cvt_pk_bf16_f32 %0, %1, %2" : "=v"(r) : "v"(a), "v"(b));
    return r;
}

// ---------------- prep: 17 blocks. blk0: adjacency; blk1..16: W^T bf16 ----------------
__global__ __launch_bounds__(256) void prep_kernel(
    const float* __restrict__ W, const float* __restrict__ adj,
    const float* __restrict__ adj2, float* __restrict__ wsf)
{
    const int t = threadIdx.x, b = blockIdx.x;
    if (b == 0) {
        for (int e = t; e < 340; e += 256) {     // padded [17][20], pads -> 0
            int i = e / 20, j = e % 20;
            float v = 0.f;
            if (j < 17) {
                v = 0.5f * (adj[i*17+j] + adj2[i*17+j] + adj[j*17+i] + adj2[j*17+i]);
                if (i == j) { wsf[OFF_DIAG + i] = v; v = 0.f; }
            }
            wsf[OFF_OFFSYM + e] = v;
        }
        return;
    }
    short* wbt = (short*)(wsf + OFF_WBT);
    const int col = (b - 1) * 16 + (t >> 4);
    const int k0  = (t & 15) * 8;
    const int sel = col >> 7, colp = col & 127;
    const float* src = W + sel * 16384 + colp;   // W[sel][k][colp]
    bf16x8 p;
    #pragma unroll
    for (int e = 0; e < 8; ++e) p[e] = f2bf(src[(k0 + e) * 128]);
    *(bf16x8*)(wbt + col * 128 + k0) = p;
}

// ---------------- conv: 68 rows/block, MFMA bf16 (R9 structure) ----------
// LDS: hhI[68*130] ints (35.4KB), aliased as A-tile short[80][136] in phase 1;
// offs [17][20] (16B-aligned rows). 3 barriers (red phase removed).
template<int USE_BF16>
__global__ __launch_bounds__(512, 4) void conv_kernel(
    const float* __restrict__ x, const float* __restrict__ M,
    const float* __restrict__ bias, float* ws,
    float* __restrict__ out, short* __restrict__ pre)
{
    __shared__ int hhI[68 * 130];
    __shared__ __align__(16) float offs[340];
    short (*A)[136] = (short(*)[136])hhI;   // 80 rows (12 zero-pad)

    const int tid = threadIdx.x;
    const int w = tid >> 6, l = tid & 63, c = l & 15, g = l >> 4;

    for (int e = tid; e < 340; e += 512) offs[e] = ws[OFF_OFFSYM + e];

    // ---- stage x[blk*68 .. +68) f32 -> bf16 LDS (2176 float4) ----
    const float4* xsrc = (const float4*)(x + (size_t)blockIdx.x * (68 * 128));
    #pragma unroll
    for (int it = 0; it < 5; ++it) {
        int f = tid + it * 512;
        if (f < 2176) {
            float4 v = xsrc[f];
            int r = f >> 5, k0 = (f & 31) << 2;
            pk4U p;
            p.u[0] = pk2(v.x, v.y);
            p.u[1] = pk2(v.z, v.w);
            *(bf16x4*)&A[r][k0] = p.v;
        }
    }
    if (tid < 408) {                       // zero pad rows 68..79 (12*136 shorts)
        bf16x4 z = {0, 0, 0, 0};
        ((bf16x4*)&A[68][0])[tid] = z;
    }
    __syncthreads();

    // ---- K-loop: wave w owns col = w*16+c for h0 (col) and h1 (col+128) ----
    const short* wbt = (const short*)(ws + OFF_WBT);
    const int col = w * 16 + c;
    f32x4 acc0[5], acc1[5];
    #pragma unroll
    for (int mt = 0; mt < 5; ++mt) {
        acc0[mt] = (f32x4){0.f, 0.f, 0.f, 0.f};
        acc1[mt] = (f32x4){0.f, 0.f, 0.f, 0.f};
    }
    #pragma unroll
    for (int ks = 0; ks < 4; ++ks) {
        bf16x8 b0 = *(const bf16x8*)(wbt + col * 128 + ks * 32 + g * 8);
        bf16x8 b1 = *(const bf16x8*)(wbt + (col + 128) * 128 + ks * 32 + g * 8);
        #pragma unroll
        for (int mt = 0; mt < 5; ++mt) {
            bf16x8 af = *(const bf16x8*)&A[mt * 16 + c][ks * 32 + g * 8];
            acc0[mt] = __builtin_amdgcn_mfma_f32_16x16x32_bf16(af, b0, acc0[mt], 0, 0, 0);
            acc1[mt] = __builtin_amdgcn_mfma_f32_16x16x32_bf16(af, b1, acc1[mt], 0, 0, 0);
        }
    }
    __syncthreads();   // all A reads done before hh overwrites the union

    // ---- epilogue (R4/R9-proven): fold diag/M/bias, pack one dword per (row,col) ----
    const float bv = bias[col];
    #pragma unroll
    for (int mt = 0; mt < 5; ++mt) {
        #pragma unroll
        for (int r = 0; r < 4; ++r) {
            int row = mt * 16 + g * 4 + r;
            if (row < 68) {
                int j = row - 17 * ((row * 241) >> 12);   // row % 17 (valid to 67)
                float m  = M[j * 128 + col];
                float dg = ws[OFF_DIAG + j];
                float lo = fmaf(dg * m, acc0[mt][r], bv); // diag*M*h0 + bias
                float hi = m * acc1[mt][r];               // M*h1
                hhI[row * 130 + col] = (int)pk2(lo, hi);
            }
        }
    }
    __syncthreads();   // hh ready

    // ---- mixing: thread -> (bb = tid>>7, o = tid&127); 17 rows each ----
    const int bb = tid >> 7, o = tid & 127;
    const int rb = bb * 17;
    int pj[17];
    #pragma unroll
    for (int i = 0; i < 17; ++i) pj[i] = hhI[(rb + i) * 130 + o];
    // no further barrier needed: hhI not reused

    float vout[17];
    #pragma unroll
    for (int q = 0; q < 17; ++q) vout[q] = bflo(pj[q]);
    #pragma unroll
    for (int j = 0; j < 17; ++j) {
        float h1v = bfhi(pj[j]);
        // off symmetric: offs[q][j] == offs[j][q]; row j is contiguous + 16B-aligned
        const f32x4* orow = (const f32x4*)&offs[j * 20];
        f32x4 o0 = orow[0], o1 = orow[1], o2 = orow[2], o3 = orow[3];
        float oz = offs[j * 20 + 16];
        vout[0]  = fmaf(o0.x, h1v, vout[0]);
        vout[1]  = fmaf(o0.y, h1v, vout[1]);
        vout[2]  = fmaf(o0.z, h1v, vout[2]);
        vout[3]  = fmaf(o0.w, h1v, vout[3]);
        vout[4]  = fmaf(o1.x, h1v, vout[4]);
        vout[5]  = fmaf(o1.y, h1v, vout[5]);
        vout[6]  = fmaf(o1.z, h1v, vout[6]);
        vout[7]  = fmaf(o1.w, h1v, vout[7]);
        vout[8]  = fmaf(o2.x, h1v, vout[8]);
        vout[9]  = fmaf(o2.y, h1v, vout[9]);
        vout[10] = fmaf(o2.z, h1v, vout[10]);
        vout[11] = fmaf(o2.w, h1v, vout[11]);
        vout[12] = fmaf(o3.x, h1v, vout[12]);
        vout[13] = fmaf(o3.y, h1v, vout[13]);
        vout[14] = fmaf(o3.z, h1v, vout[14]);
        vout[15] = fmaf(o3.w, h1v, vout[15]);
        vout[16] = fmaf(oz,   h1v, vout[16]);
    }

    float s = 0.f, s2 = 0.f;
    const size_t gbase = ((size_t)blockIdx.x * 68 + rb) * 128 + o;
    #pragma unroll
    for (int q = 0; q < 17; ++q) {
        float v = vout[q];
        if (USE_BF16) pre[gbase + (size_t)q * 128] = (short)pk2(v, v);
        else          out[gbase + (size_t)q * 128] = v;
        s += v; s2 = fmaf(v, v, s2);
    }

    // ---- BN partials: direct per-thread atomics (<=64 adds/address grid-wide) ----
    float* slot = ws + OFF_PART + ((blockIdx.x & (NSLOT - 1)) << 8);
    atomicAdd(slot + o, s);
    atomicAdd(slot + 128 + o, s2);
}

// ---------------- BN stats reduce ----------------
__global__ __launch_bounds__(256) void bn_reduce_kernel(
    const float* __restrict__ part, const float* __restrict__ gamma,
    const float* __restrict__ beta, float* __restrict__ stats)
{
    const int t = threadIdx.x;             // 0..255
    float s = 0.f;
    #pragma unroll 8
    for (int i = 0; i < NSLOT; ++i) s += part[i * 256 + t];
    __shared__ float tot[256];
    tot[t] = s;
    __syncthreads();
    if (t < 128) {
        const float n = 139264.f;          // 8192*17
        float mean = tot[t] / n;
        float var  = tot[t + 128] / n - mean * mean;
        var = fmaxf(var, 0.f);
        float inv = rsqrtf(var + 1e-5f);
        float sc = gamma[t] * inv;
        stats[t] = sc;
        stats[t + 128] = beta[t] - mean * sc;
    }
}

// ---------------- BN apply + relu: bf16 pre (ws) -> f32 out ----------------
__global__ __launch_bounds__(256) void apply_bf16_kernel(
    const short* __restrict__ pre, const float* __restrict__ stats,
    float* __restrict__ out)
{
    const int tid = blockIdx.x * 256 + threadIdx.x;
    const int c0 = (tid << 3) & 127;       // stride (524288*8) % 128 == 0
    float sc[8], sh[8];
    #pragma unroll
    for (int e = 0; e < 8; ++e) { sc[e] = stats[c0 + e]; sh[e] = stats[128 + c0 + e]; }
    const bf16x8* p8 = (const bf16x8*)pre;
    for (int q = tid; q < 2228224; q += 524288) {
        bf16x8 v = p8[q];
        float4 o0, o1;
        o0.x = fmaxf(fmaf(bf2f(v[0]), sc[0], sh[0]), 0.f);
        o0.y = fmaxf(fmaf(bf2f(v[1]), sc[1], sh[1]), 0.f);
        o0.z = fmaxf(fmaf(bf2f(v[2]), sc[2], sh[2]), 0.f);
        o0.w = fmaxf(fmaf(bf2f(v[3]), sc[3], sh[3]), 0.f);
        o1.x = fmaxf(fmaf(bf2f(v[4]), sc[4], sh[4]), 0.f);
        o1.y = fmaxf(fmaf(bf2f(v[5]), sc[5], sh[5]), 0.f);
        o1.z = fmaxf(fmaf(bf2f(v[6]), sc[6], sh[6]), 0.f);
        o1.w = fmaxf(fmaf(bf2f(v[7]), sc[7], sh[7]), 0.f);
        float4* dst = (float4*)(out + (size_t)q * 8);
        dst[0] = o0; dst[1] = o1;
    }
}

// ---------------- BN apply + relu fallback (in-place f32) ----------------
__global__ __launch_bounds__(256) void apply_kernel(
    float* __restrict__ out, const float* __restrict__ stats, int n4)
{
    const int tid = blockIdx.x * 256 + threadIdx.x;
    const int c0 = (tid << 2) & 127;
    const float sc0 = stats[c0],     sc1 = stats[c0 + 1],
                sc2 = stats[c0 + 2], sc3 = stats[c0 + 3];
    const float sh0 = stats[128 + c0],     sh1 = stats[128 + c0 + 1],
                sh2 = stats[128 + c0 + 2], sh3 = stats[128 + c0 + 3];
    float4* o4 = (float4*)out;
    for (int q = tid; q < n4; q += 2048 * 256) {
        float4 v = o4[q];
        v.x = fmaxf(fmaf(v.x, sc0, sh0), 0.f);
        v.y = fmaxf(fmaf(v.y, sc1, sh1), 0.f);
        v.z = fmaxf(fmaf(v.z, sc2, sh2), 0.f);
        v.w = fmaxf(fmaf(v.w, sc3, sh3), 0.f);
        o4[q] = v;
    }
}

extern "C" void kernel_launch(void* const* d_in, const int* in_sizes, int n_in,
                              void* d_out, int out_size, void* d_ws, size_t ws_size,
                              hipStream_t stream) {
    (void)in_sizes; (void)n_in; (void)out_size;
    const float* x     = (const float*)d_in[0];
    const float* W     = (const float*)d_in[1];
    const float* M     = (const float*)d_in[2];
    const float* adj   = (const float*)d_in[3];
    const float* adj2  = (const float*)d_in[4];
    const float* bias  = (const float*)d_in[5];
    const float* gamma = (const float*)d_in[6];
    const float* beta  = (const float*)d_in[7];
    float* out = (float*)d_out;
    float* wsf = (float*)d_ws;
    short* pre = (short*)(wsf + OFF_PRE);

    const bool big = ws_size >= (size_t)OFF_PRE * 4 + PRE_SHORTS * 2;

    (void)hipMemsetAsync(d_ws, 0, NSLOT * 256 * sizeof(float), stream);   // BN partials
    prep_kernel<<<17, 256, 0, stream>>>(W, adj, adj2, wsf);
    if (big) {
        conv_kernel<1><<<2048, 512, 0, stream>>>(x, M, bias, wsf, out, pre);
        bn_reduce_kernel<<<1, 256, 0, stream>>>(wsf + OFF_PART, gamma, beta, wsf + OFF_STATS);
        apply_bf16_kernel<<<2048, 256, 0, stream>>>(pre, wsf + OFF_STATS, out);
    } else {
        conv_kernel<0><<<2048, 512, 0, stream>>>(x, M, bias, wsf, out, pre);
        bn_reduce_kernel<<<1, 256, 0, stream>>>(wsf + OFF_PART, gamma, beta, wsf + OFF_STATS);
        apply_kernel<<<2048, 256, 0, stream>>>(out, wsf + OFF_STATS, 4456448);
    }
}